// Round 6
// baseline (62.134 us; speedup 1.0000x reference)
//
#include <hip/hip_runtime.h>

// Rx_layer: out = (⊗_q Rx(θ_{blk,q})) · state, per (batch, block).
// BATCH=32, N_BLOCKS=8, N_QUBITS=11, DIM=2048.
//
// IO MODEL (R6, "model C"):
//   state   : f32[524288] (32,8,1,2048,1)  -- 2 MB   [R5's NaN proves f32:
//             bf16-reads of true-f32 low halves hit exp=0xFF -> NaN]
//   weights : f32[88]     (1,8,1,11,1,1)
//   d_out   : f32[524288] -- REAL PARTS of the complex64 result, 2 MB.
//             complex64.astype(float32) drops imag; out_size counts complex
//             elements. Retro-dicts all rounds: R1 4MB write faulted (buffer
//             2MB); R2 ushort2(re,im) read as f32 decodes to ~imag values ->
//             independence absmax 4.625 vs real-part ref; R3/R4 packed bf16
//             pairs decode to misplaced reals -> 4.797/5.047.
//
// One wave (64 lanes) owns one 2048-amplitude state vector:
//   amp index i = (r<<6) | lane,  r in [0,32).
// kron chain = iterated np.kron(U, m_q) -> qubit q sits on bit (10-q);
// gate on bit t uses angle theta[10-t].  (Verified numerically on a Q=2
// basis-state example: positions and signs all match.)
// Rx = [[a,-ib],[-ib,a]] symmetric -> both halves of a pair update as
//   re' = a*re + b*im_partner ; im' = a*im - b*re_partner  (uniform, no branch)
// bits 6..10: partner is another register (compile-time pairing)
// bits 0..5 : partner is another lane (__shfl_xor)

#define QB     11
#define DIM    2048
#define NB     8
#define BATCHN 32
#define RPT    32   // DIM / 64 lanes

__global__ __launch_bounds__(64) void rx_layer_kernel(
    const float* __restrict__ state,
    const float* __restrict__ weights,
    float* __restrict__ out)     // f32 real parts, (batch,blk,amp) order
{
    const int lane = threadIdx.x;          // 0..63
    const int pair = blockIdx.x;           // batch*8 + blk, 0..255
    const int blk  = pair & (NB - 1);
    const long base = (long)pair * DIM;

    // ---- load: state is real f32; imag starts at 0 ----
    float re[RPT], im[RPT];
#pragma unroll
    for (int r = 0; r < RPT; ++r) {
        re[r] = state[base + (r << 6) + lane];
        im[r] = 0.0f;
    }

    // ---- angles: gate on bit t uses qubit q = 10 - t ----
    float av[QB], bv[QB];
#pragma unroll
    for (int t = 0; t < QB; ++t) {
        float w = weights[blk * QB + (QB - 1 - t)];
        float s, c;
        __sincosf(0.5f * w, &s, &c);
        av[t] = c;
        bv[t] = s;
    }

    // ---- gates on bits 6..10: register-pair mixes (compile-time pairing) ----
#pragma unroll
    for (int t = 6; t < QB; ++t) {
        const int rs = 1 << (t - 6);
        const float a = av[t], b = bv[t];
#pragma unroll
        for (int r0 = 0; r0 < RPT; ++r0) {
            if (r0 & rs) continue;     // folds at compile time
            const int r1 = r0 + rs;
            const float xr = re[r0], xi = im[r0];
            const float yr = re[r1], yi = im[r1];
            re[r0] = a * xr + b * yi;
            im[r0] = a * xi - b * yr;
            re[r1] = a * yr + b * xi;
            im[r1] = a * yi - b * xr;
        }
    }

    // ---- gates on bits 0..5: cross-lane via shfl_xor (symmetric update) ----
#pragma unroll
    for (int t = 0; t < 6; ++t) {
        const int mask = 1 << t;
        const float a = av[t], b = bv[t];
#pragma unroll
        for (int r = 0; r < RPT; ++r) {
            const float pr = __shfl_xor(re[r], mask, 64);
            const float pi = __shfl_xor(im[r], mask, 64);
            re[r] = a * re[r] + b * pi;
            im[r] = a * im[r] - b * pr;
        }
    }

    // ---- store: f32 REAL PARTS only, coalesced 4B/lane, exactly 2 MB ----
#pragma unroll
    for (int r = 0; r < RPT; ++r) {
        out[base + (r << 6) + lane] = re[r];
    }
}

extern "C" void kernel_launch(void* const* d_in, const int* in_sizes, int n_in,
                              void* d_out, int out_size, void* d_ws, size_t ws_size,
                              hipStream_t stream)
{
    const float* state   = (const float*)d_in[0];
    const float* weights = (const float*)d_in[1];
    if (n_in >= 2 && in_sizes[0] == NB * QB) {  // defensive: swapped order
        state   = (const float*)d_in[1];
        weights = (const float*)d_in[0];
    }
    float* out = (float*)d_out;  // 524288 f32 = real parts

    rx_layer_kernel<<<BATCHN * NB, 64, 0, stream>>>(state, weights, out);
}

// Round 7
// 59.516 us; speedup vs baseline: 1.0440x; 1.0440x over previous
//
#include <hip/hip_runtime.h>

// Rx_layer: out = Re[(⊗_q Rx(θ_{blk,q})) · state], per (batch, block).
// BATCH=32, N_BLOCKS=8, N_QUBITS=11, DIM=2048.
//
// IO MODEL (verified PASS in R6):
//   state   : f32[524288] (32,8,1,2048,1)  -- 2 MB
//   weights : f32[88]     (1,8,1,11,1,1)
//   d_out   : f32[524288] -- REAL PARTS of the complex64 result
//             (complex64.astype(float32) drops imag), 2 MB.
//
// One wave (64 lanes) owns one 2048-amplitude state vector, float4 I/O:
//   amp = (r<<8) | (lane<<2) | j,   r in [0,8), lane in [0,64), j in [0,4).
// kron chain = iterated np.kron(U, m_q) -> qubit q sits on bit (10-q);
// gate on bit t uses angle theta[10-t]. All 11 Rx gates commute (distinct
// bits), so stage order is free:
//   bits 0-1  : j-register pairs (compile-time)
//   bits 2-7  : cross-lane __shfl_xor, mask = 1<<(t-2)
//   bits 8-10 : r-register pairs (compile-time)
// Rx = [[a,-ib],[-ib,a]] symmetric -> both halves of a pair update as
//   re' = a*re + b*im_partner ; im' = a*im - b*re_partner  (uniform, no branch)
//
// R6 counters: dur_us=62 dominated by harness reset (268MB ws poison = 40us
// fill @83% HBM peak + restores + launch overhead); kernel itself ~1-2us.
// This round: float4 I/O (8 dwordx4 loads + 8 dwordx4 stores) to shave the
// only controllable term. If dur_us stays ~62, we are at the harness floor.

#define QB     11
#define DIM    2048
#define NB     8
#define BATCHN 32
#define R4     8    // float4 registers per lane (8*4 = 32 amps/lane)

__global__ __launch_bounds__(64) void rx_layer_kernel(
    const float4* __restrict__ state,    // 524288/4 float4
    const float*  __restrict__ weights,
    float4* __restrict__ out)            // f32 real parts, float4-packed
{
    const int lane = threadIdx.x;          // 0..63
    const int pair = blockIdx.x;           // batch*8 + blk, 0..255
    const int blk  = pair & (NB - 1);
    const long base4 = (long)pair * (DIM / 4);   // 512 float4 per state

    // ---- load: state is real f32 (float4 = 16B/lane); imag starts at 0 ----
    float re[R4][4], im[R4][4];
#pragma unroll
    for (int r = 0; r < R4; ++r) {
        const float4 v = state[base4 + (r << 6) + lane];
        re[r][0] = v.x; re[r][1] = v.y; re[r][2] = v.z; re[r][3] = v.w;
        im[r][0] = im[r][1] = im[r][2] = im[r][3] = 0.0f;
    }

    // ---- angles: gate on bit t uses qubit q = 10 - t ----
    float av[QB], bv[QB];
#pragma unroll
    for (int t = 0; t < QB; ++t) {
        float w = weights[blk * QB + (QB - 1 - t)];
        float s, c;
        __sincosf(0.5f * w, &s, &c);
        av[t] = c;
        bv[t] = s;
    }

    // ---- gates on bits 0..1: j-register pairs ----
#pragma unroll
    for (int t = 0; t < 2; ++t) {
        const int js = 1 << t;
        const float a = av[t], b = bv[t];
#pragma unroll
        for (int r = 0; r < R4; ++r) {
#pragma unroll
            for (int j0 = 0; j0 < 4; ++j0) {
                if (j0 & js) continue;   // folds at compile time
                const int j1 = j0 + js;
                const float xr = re[r][j0], xi = im[r][j0];
                const float yr = re[r][j1], yi = im[r][j1];
                re[r][j0] = a * xr + b * yi;
                im[r][j0] = a * xi - b * yr;
                re[r][j1] = a * yr + b * xi;
                im[r][j1] = a * yi - b * xr;
            }
        }
    }

    // ---- gates on bits 2..7: cross-lane shfl_xor (symmetric update) ----
#pragma unroll
    for (int t = 2; t < 8; ++t) {
        const int mask = 1 << (t - 2);
        const float a = av[t], b = bv[t];
#pragma unroll
        for (int r = 0; r < R4; ++r) {
#pragma unroll
            for (int j = 0; j < 4; ++j) {
                const float pr = __shfl_xor(re[r][j], mask, 64);
                const float pi = __shfl_xor(im[r][j], mask, 64);
                re[r][j] = a * re[r][j] + b * pi;
                im[r][j] = a * im[r][j] - b * pr;
            }
        }
    }

    // ---- gates on bits 8..10: r-register pairs ----
#pragma unroll
    for (int t = 8; t < QB; ++t) {
        const int rs = 1 << (t - 8);
        const float a = av[t], b = bv[t];
#pragma unroll
        for (int r0 = 0; r0 < R4; ++r0) {
            if (r0 & rs) continue;       // folds at compile time
            const int r1 = r0 + rs;
#pragma unroll
            for (int j = 0; j < 4; ++j) {
                const float xr = re[r0][j], xi = im[r0][j];
                const float yr = re[r1][j], yi = im[r1][j];
                re[r0][j] = a * xr + b * yi;
                im[r0][j] = a * xi - b * yr;
                re[r1][j] = a * yr + b * xi;
                im[r1][j] = a * yi - b * xr;
            }
        }
    }

    // ---- store: f32 REAL PARTS only, float4-packed, 16B/lane ----
#pragma unroll
    for (int r = 0; r < R4; ++r) {
        float4 v;
        v.x = re[r][0]; v.y = re[r][1]; v.z = re[r][2]; v.w = re[r][3];
        out[base4 + (r << 6) + lane] = v;
    }
}

extern "C" void kernel_launch(void* const* d_in, const int* in_sizes, int n_in,
                              void* d_out, int out_size, void* d_ws, size_t ws_size,
                              hipStream_t stream)
{
    const void* p0 = d_in[0];
    const void* p1 = d_in[1];
    const float4* state  = (const float4*)p0;
    const float*  weights = (const float*)p1;
    if (n_in >= 2 && in_sizes[0] == NB * QB) {  // defensive: swapped order
        state   = (const float4*)p1;
        weights = (const float*)p0;
    }
    float4* out = (float4*)d_out;  // 524288 f32 real parts

    rx_layer_kernel<<<BATCHN * NB, 64, 0, stream>>>(state, weights, out);
}